// Round 1
// baseline (505.278 us; speedup 1.0000x reference)
//
#include <hip/hip_runtime.h>
#include <stdint.h>

#define B_ 2
#define S_ 2048
#define DM_ 2048
#define H_ 32
#define KVH_ 8
#define HD_ 64

typedef unsigned short u16;
typedef __attribute__((ext_vector_type(8))) short bf16x8;
typedef __attribute__((ext_vector_type(4))) float f32x4;

static __device__ __forceinline__ u16 f2bf(float f) {
  unsigned int u = __float_as_uint(f);
  u = (u + 0x7fffu + ((u >> 16) & 1u)) >> 16;
  return (u16)u;
}

// global -> LDS direct (width 16). LDS dest = wave-uniform base + lane*16.
static __device__ __forceinline__ void gload16(const void* g, void* lds_wave_base) {
  __builtin_amdgcn_global_load_lds(
      (__attribute__((address_space(1))) unsigned int*)(uintptr_t)g,
      (__attribute__((address_space(3))) unsigned int*)(uintptr_t)lds_wave_base,
      16, 0, 0);
}

// ---------------- fp32 -> bf16 convert ----------------
__global__ void cvt_bf16(const float* __restrict__ in, u16* __restrict__ out, int n4) {
  int i = blockIdx.x * blockDim.x + threadIdx.x;
  if (i >= n4) return;
  const float4 v = ((const float4*)in)[i];
  ushort4 o;
  o.x = f2bf(v.x); o.y = f2bf(v.y); o.z = f2bf(v.z); o.w = f2bf(v.w);
  ((ushort4*)out)[i] = o;
}

// ---------------- GEMM: C(MxN) = A(MxK) * B(NxK)^T, bf16 in, fp32 out -------
#define BM 128
#define BN 128
#define BK 32

__global__ __launch_bounds__(256) void gemm_bt(const u16* __restrict__ A,
                                               const u16* __restrict__ Bw,
                                               float* __restrict__ C,
                                               int M, int N, int K) {
  __shared__ u16 As[BM * BK];  // row-major, 64B rows
  __shared__ u16 Bs[BN * BK];
  const int t = threadIdx.x;
  const int lane = t & 63;
  const int w = t >> 6;
  const int wr = (w >> 1) * 64, wc = (w & 1) * 64;
  const int m0 = blockIdx.y * BM;
  const int n0 = blockIdx.x * BN;

  f32x4 acc[4][4] = {};

  const char* Ab = (const char*)A;
  const char* Bb = (const char*)Bw;
  const size_t K2 = (size_t)K * 2;

  for (int k0 = 0; k0 < K; k0 += BK) {
#pragma unroll
    for (int i = 0; i < 2; i++) {
      const int P = i * 4096 + t * 16;        // this lane's LDS byte dest
      const int Pb = i * 4096 + (w << 10);    // wave-uniform base
      const int row = P >> 6;                 // 64B per staged row (BK=32 bf16)
      const int kb = P & 63;
      gload16(Ab + (size_t)(m0 + row) * K2 + (size_t)k0 * 2 + kb, (char*)As + Pb);
      gload16(Bb + (size_t)(n0 + row) * K2 + (size_t)k0 * 2 + kb, (char*)Bs + Pb);
    }
    __syncthreads();
    bf16x8 af[4], bfr[4];
#pragma unroll
    for (int m = 0; m < 4; m++)
      af[m] = *(const bf16x8*)((const char*)As +
               (wr + m * 16 + (lane & 15)) * 64 + ((lane >> 4) << 4));
#pragma unroll
    for (int n = 0; n < 4; n++)
      bfr[n] = *(const bf16x8*)((const char*)Bs +
               (wc + n * 16 + (lane & 15)) * 64 + ((lane >> 4) << 4));
#pragma unroll
    for (int m = 0; m < 4; m++)
#pragma unroll
      for (int n = 0; n < 4; n++)
        acc[m][n] = __builtin_amdgcn_mfma_f32_16x16x32_bf16(af[m], bfr[n], acc[m][n], 0, 0, 0);
    __syncthreads();
  }

#pragma unroll
  for (int m = 0; m < 4; m++) {
    const int r0 = m0 + wr + m * 16 + ((lane >> 4) << 2);
#pragma unroll
    for (int n = 0; n < 4; n++) {
      const int c = n0 + wc + n * 16 + (lane & 15);
#pragma unroll
      for (int j = 0; j < 4; j++)
        C[(size_t)(r0 + j) * N + c] = acc[m][n][j];
    }
  }
}

// ---------------- fused RMSNorm + RoPE, fp32 -> bf16, (b,s,h,d)->(b,h,s,d) --
__global__ void fuse_norm_rope(const float* __restrict__ In, const float* __restrict__ cosT,
                               const float* __restrict__ sinT, const float* __restrict__ wgt,
                               u16* __restrict__ OutT, int NH, float oscale) {
  const int r = blockIdx.x * 4 + (threadIdx.x >> 6);  // row over (b,s,h)
  const int lane = threadIdx.x & 63;
  const int h = r % NH;
  const int bs = r / NH;
  const int s = bs & (S_ - 1);
  const int b = bs >> 11;  // S_ = 2048
  float x = In[(size_t)r * 64 + lane];
  float ss = x * x;
#pragma unroll
  for (int m = 1; m < 64; m <<= 1) ss += __shfl_xor(ss, m, 64);
  float xn = x * rsqrtf(ss * (1.0f / 64.0f) + 1e-6f) * wgt[lane];
  float pr = __shfl_xor(xn, 32, 64);
  float o = xn * cosT[s * 64 + lane] + (lane < 32 ? -pr : pr) * sinT[s * 64 + lane];
  OutT[(((size_t)(b * NH + h)) * S_ + s) * 64 + lane] = f2bf(o * oscale);
}

// ---------------- V: fp32 (b,s,kvh,d) -> bf16 (b,kvh,d,s) -------------------
__global__ void v_transpose(const float* __restrict__ Vf, u16* __restrict__ Vt) {
  __shared__ u16 tile[64][72];
  const int s0 = blockIdx.x * 64;
  const int bk = blockIdx.y;
  const int b = bk / KVH_, kvh = bk % KVH_;
  const int t = threadIdx.x;
#pragma unroll
  for (int it = 0; it < 16; it++) {
    int idx = it * 256 + t;
    int sl = idx >> 6, d = idx & 63;
    tile[sl][d] = f2bf(Vf[((size_t)(b * S_ + s0 + sl)) * (KVH_ * HD_) + kvh * HD_ + d]);
  }
  __syncthreads();
#pragma unroll
  for (int it = 0; it < 16; it++) {
    int idx = it * 256 + t;
    int d = idx >> 6, sl = idx & 63;
    Vt[(((size_t)(b * KVH_ + kvh)) * HD_ + d) * S_ + s0 + sl] = tile[sl][d];
  }
}

// ---------------- flash attention, causal GQA -------------------------------
// grid: (S/64, B*H); 4 waves, each owns 16 q-rows. Q pre-scaled by log2e/8.
__global__ __launch_bounds__(256) void attn_fwd(const u16* __restrict__ Qt,
                                                const u16* __restrict__ Kt,
                                                const u16* __restrict__ Vt,
                                                u16* __restrict__ Out) {
  __shared__ u16 Ksm[64 * 64];      // [key][d], XOR-swizzled rows (128B)
  __shared__ u16 Vsm[64 * 64];      // [d][key], XOR-swizzled rows
  __shared__ u16 Psm[4 * 16 * 64];  // per-wave P tile, swizzled

  const int t = threadIdx.x, lane = t & 63, w = t >> 6;
  const int qt = blockIdx.x;
  const int bh = blockIdx.y;
  const int b = bh / H_, h = bh % H_, kvh = h >> 2;  // NREP=4
  const int q0 = qt * 64 + w * 16;

  // Q fragments (A-operand): lane holds Q[q0+(lane&15)][k=(lane>>4)*8 + j]
  bf16x8 aq[2];
  {
    const u16* qp = Qt + (((size_t)(b * H_ + h)) * S_ + q0 + (lane & 15)) * HD_ + ((lane >> 4) << 3);
    aq[0] = *(const bf16x8*)qp;
    aq[1] = *(const bf16x8*)(qp + 32);
  }

  f32x4 o_acc[4] = {};
  float m_i[4], l_i[4];
#pragma unroll
  for (int j = 0; j < 4; j++) { m_i[j] = -1e30f; l_i[j] = 0.0f; }

  const char* Kb = (const char*)(Kt + ((size_t)(b * KVH_ + kvh)) * S_ * HD_);
  const char* Vb = (const char*)(Vt + ((size_t)(b * KVH_ + kvh)) * HD_ * S_);

  for (int kt = 0; kt <= qt; kt++) {
    // stage K,V: linear LDS dest, inverse-swizzled global source
#pragma unroll
    for (int i = 0; i < 2; i++) {
      const int P = i * 4096 + t * 16;
      const int Pb = i * 4096 + (w << 10);
      const int row = P >> 7;                          // 128B logical rows
      const int cb = (P ^ ((row & 7) << 4)) & 127;     // swizzled source column byte
      gload16(Kb + (size_t)(kt * 64 + row) * 128 + cb, (char*)Ksm + Pb);
      gload16(Vb + (size_t)row * (S_ * 2) + (size_t)kt * 128 + cb, (char*)Vsm + Pb);
    }
    __syncthreads();

    // scores: S[q][kk] = sum_d Q[q][d] K[kk][d]
    f32x4 sc[4];
#pragma unroll
    for (int nt = 0; nt < 4; nt++) {
      f32x4 s = {};
      const int kk = nt * 16 + (lane & 15);
#pragma unroll
      for (int hh = 0; hh < 2; hh++) {
        const int byt = (kk * 128 + hh * 64 + ((lane >> 4) << 4)) ^ ((kk & 7) << 4);
        bf16x8 bk = *(const bf16x8*)((const char*)Ksm + byt);
        s = __builtin_amdgcn_mfma_f32_16x16x32_bf16(aq[hh], bk, s, 0, 0, 0);
      }
      sc[nt] = s;
    }

    // online softmax (log2 domain; Q carries the 1/8*log2e scale)
    const bool diag = (kt == qt);
    float tmax[4];
#pragma unroll
    for (int j = 0; j < 4; j++) tmax[j] = -1e30f;
#pragma unroll
    for (int nt = 0; nt < 4; nt++) {
      const int kkg = kt * 64 + nt * 16 + (lane & 15);
#pragma unroll
      for (int j = 0; j < 4; j++) {
        float v = sc[nt][j];
        const int qg = q0 + ((lane >> 4) << 2) + j;
        if (diag && kkg > qg) v = -1e30f;
        sc[nt][j] = v;
        tmax[j] = fmaxf(tmax[j], v);
      }
    }
#pragma unroll
    for (int j = 0; j < 4; j++) {
      float v = tmax[j];
      v = fmaxf(v, __shfl_xor(v, 1, 16));
      v = fmaxf(v, __shfl_xor(v, 2, 16));
      v = fmaxf(v, __shfl_xor(v, 4, 16));
      v = fmaxf(v, __shfl_xor(v, 8, 16));
      const float mnew = fmaxf(m_i[j], v);
      tmax[j] = exp2f(m_i[j] - mnew);  // alpha
      m_i[j] = mnew;
    }
    // P = exp2(s - m), write to per-wave swizzled LDS, accumulate row sums
    float rsum[4] = {0.f, 0.f, 0.f, 0.f};
#pragma unroll
    for (int nt = 0; nt < 4; nt++) {
#pragma unroll
      for (int j = 0; j < 4; j++) {
        const float p = exp2f(sc[nt][j] - m_i[j]);
        rsum[j] += p;
        const int qrow = ((lane >> 4) << 2) + j;
        const int byt = (qrow * 128 + (nt * 16 + (lane & 15)) * 2) ^ ((qrow & 7) << 4);
        *(u16*)((char*)Psm + w * 2048 + byt) = f2bf(p);
      }
    }
#pragma unroll
    for (int j = 0; j < 4; j++) {
      float v = rsum[j];
      v += __shfl_xor(v, 1, 16);
      v += __shfl_xor(v, 2, 16);
      v += __shfl_xor(v, 4, 16);
      v += __shfl_xor(v, 8, 16);
      l_i[j] = l_i[j] * tmax[j] + v;
    }
#pragma unroll
    for (int dt = 0; dt < 4; dt++)
#pragma unroll
      for (int j = 0; j < 4; j++) o_acc[dt][j] *= tmax[j];

    asm volatile("s_waitcnt lgkmcnt(0)" ::: "memory");  // P writes -> P reads (same wave)

    // PV: O[q][d] += P[q][kk] V[kk][d]
#pragma unroll
    for (int hh = 0; hh < 2; hh++) {
      const int q = lane & 15;
      const int pb = (q * 128 + hh * 64 + ((lane >> 4) << 4)) ^ ((q & 7) << 4);
      bf16x8 pa = *(const bf16x8*)((const char*)Psm + w * 2048 + pb);
#pragma unroll
      for (int dt = 0; dt < 4; dt++) {
        const int d = dt * 16 + (lane & 15);
        const int vbyt = (d * 128 + hh * 64 + ((lane >> 4) << 4)) ^ ((d & 7) << 4);
        bf16x8 bv = *(const bf16x8*)((const char*)Vsm + vbyt);
        o_acc[dt] = __builtin_amdgcn_mfma_f32_16x16x32_bf16(pa, bv, o_acc[dt], 0, 0, 0);
      }
    }
    __syncthreads();
  }

  // epilogue: O /= l, write bf16 (b,s,h,d)
#pragma unroll
  for (int j = 0; j < 4; j++) {
    const int q = q0 + ((lane >> 4) << 2) + j;
    const float inv = 1.0f / l_i[j];
#pragma unroll
    for (int dt = 0; dt < 4; dt++)
      Out[(((size_t)b * S_ + q) * H_ + h) * HD_ + dt * 16 + (lane & 15)] =
          f2bf(o_acc[dt][j] * inv);
  }
}

// ---------------- host launch ----------------
extern "C" void kernel_launch(void* const* d_in, const int* in_sizes, int n_in,
                              void* d_out, int out_size, void* d_ws, size_t ws_size,
                              hipStream_t stream) {
  const float* x  = (const float*)d_in[0];
  const float* rc = (const float*)d_in[1];
  const float* rs = (const float*)d_in[2];
  const float* Wq = (const float*)d_in[3];
  const float* Wk = (const float*)d_in[4];
  const float* Wv = (const float*)d_in[5];
  const float* Wo = (const float*)d_in[6];
  const float* qw = (const float*)d_in[7];
  const float* kw = (const float*)d_in[8];
  float* out = (float*)d_out;

  char* ws = (char*)d_ws;
  const size_t MB = (size_t)1 << 20;
  u16*   xb  = (u16*)(ws + 0 * MB);    // 16 MB bf16 x      (reused as attn-out)
  u16*   wb  = (u16*)(ws + 16 * MB);   // 8 MB  bf16 weight slot (reused 4x)
  float* Kf  = (float*)(ws + 24 * MB); // 8 MB  fp32 K-proj
  float* Vf  = (float*)(ws + 32 * MB); // 8 MB  fp32 V-proj
  u16*   Qtb = (u16*)(ws + 40 * MB);   // 16 MB bf16 Q (b,h,s,d)
  u16*   Ktb = (u16*)(ws + 56 * MB);   // 4 MB  bf16 K (b,kvh,s,d)
  u16*   Vtb = (u16*)(ws + 60 * MB);   // 4 MB  bf16 V (b,kvh,d,s)  -> 64 MB total
  float* Qf  = out;                    // d_out (32 MB fp32) doubles as Q-proj scratch
  u16*   AO  = xb;                     // xb slot free after V GEMM

  const int MT = B_ * S_;              // 4096 rows
  const float QSC = 0.125f * 1.44269504089f;  // (1/sqrt(64)) * log2(e)

  cvt_bf16<<<dim3(MT * DM_ / 1024), 256, 0, stream>>>(x, xb, MT * DM_ / 4);

  // Q path
  cvt_bf16<<<dim3(DM_ * DM_ / 1024), 256, 0, stream>>>(Wq, wb, DM_ * DM_ / 4);
  gemm_bt<<<dim3(DM_ / BN, MT / BM), 256, 0, stream>>>(xb, wb, Qf, MT, DM_, DM_);
  fuse_norm_rope<<<dim3(MT * H_ / 4), 256, 0, stream>>>(Qf, rc, rs, qw, Qtb, H_, QSC);

  // K path
  cvt_bf16<<<dim3(KVH_ * HD_ * DM_ / 1024), 256, 0, stream>>>(Wk, wb, KVH_ * HD_ * DM_ / 4);
  gemm_bt<<<dim3(KVH_ * HD_ / BN, MT / BM), 256, 0, stream>>>(xb, wb, Kf, MT, KVH_ * HD_, DM_);
  fuse_norm_rope<<<dim3(MT * KVH_ / 4), 256, 0, stream>>>(Kf, rc, rs, kw, Ktb, KVH_, 1.0f);

  // V path
  cvt_bf16<<<dim3(KVH_ * HD_ * DM_ / 1024), 256, 0, stream>>>(Wv, wb, KVH_ * HD_ * DM_ / 4);
  gemm_bt<<<dim3(KVH_ * HD_ / BN, MT / BM), 256, 0, stream>>>(xb, wb, Vf, MT, KVH_ * HD_, DM_);
  v_transpose<<<dim3(S_ / 64, B_ * KVH_), 256, 0, stream>>>(Vf, Vtb);

  // attention
  attn_fwd<<<dim3(S_ / 64, B_ * H_), 256, 0, stream>>>(Qtb, Ktb, Vtb, AO);

  // output projection -> d_out
  cvt_bf16<<<dim3(DM_ * DM_ / 1024), 256, 0, stream>>>(Wo, wb, DM_ * DM_ / 4);
  gemm_bt<<<dim3(DM_ / BN, MT / BM), 256, 0, stream>>>(AO, wb, out, MT, DM_, DM_);
}

// Round 2
// 391.133 us; speedup vs baseline: 1.2918x; 1.2918x over previous
//
#include <hip/hip_runtime.h>
#include <stdint.h>

#define B_ 2
#define S_ 2048
#define DM_ 2048
#define H_ 32
#define KVH_ 8
#define HD_ 64

typedef unsigned short u16;
typedef __attribute__((ext_vector_type(8))) short bf16x8;
typedef __attribute__((ext_vector_type(4))) float f32x4;

static __device__ __forceinline__ u16 f2bf(float f) {
  unsigned int u = __float_as_uint(f);
  u = (u + 0x7fffu + ((u >> 16) & 1u)) >> 16;
  return (u16)u;
}

// global -> LDS direct (width 16). LDS dest = wave-uniform base + lane*16.
static __device__ __forceinline__ void gload16(const void* g, void* lds_wave_base) {
  __builtin_amdgcn_global_load_lds(
      (__attribute__((address_space(1))) unsigned int*)(uintptr_t)g,
      (__attribute__((address_space(3))) unsigned int*)(uintptr_t)lds_wave_base,
      16, 0, 0);
}

// ---------------- fp32 -> bf16 convert ----------------
__global__ void cvt_bf16(const float* __restrict__ in, u16* __restrict__ out, int n4) {
  int i = blockIdx.x * blockDim.x + threadIdx.x;
  if (i >= n4) return;
  const float4 v = ((const float4*)in)[i];
  ushort4 o;
  o.x = f2bf(v.x); o.y = f2bf(v.y); o.z = f2bf(v.z); o.w = f2bf(v.w);
  ((ushort4*)out)[i] = o;
}

// ---------------- GEMM: C(MxN) = A(MxK) * B(NxK)^T, bf16 in, fp32 out -------
// 128x128 tile, 2-phase double-buffered staging (T3 minimum).
#define BM 128
#define BN 128
#define BK 32

__global__ __launch_bounds__(256) void gemm_bt(const u16* __restrict__ A,
                                               const u16* __restrict__ Bw,
                                               float* __restrict__ C,
                                               int M, int N, int K) {
  __shared__ u16 As[2][BM * BK];  // 64B rows
  __shared__ u16 Bs[2][BN * BK];
  const int t = threadIdx.x;
  const int lane = t & 63;
  const int w = t >> 6;
  const int wr = (w >> 1) * 64, wc = (w & 1) * 64;
  const int m0 = blockIdx.y * BM;
  const int n0 = blockIdx.x * BN;

  f32x4 acc[4][4] = {};

  const char* Ab = (const char*)A;
  const char* Bb = (const char*)Bw;
  const size_t K2 = (size_t)K * 2;

  const int P0 = t * 16;
  const int row0 = P0 >> 6, kb0 = P0 & 63;
  const int P1 = 4096 + t * 16;
  const int row1 = P1 >> 6, kb1 = P1 & 63;
  const int Pb0 = (w << 10), Pb1 = 4096 + (w << 10);

  auto STAGE = [&](int buf, int k0) {
    gload16(Ab + (size_t)(m0 + row0) * K2 + (size_t)k0 * 2 + kb0, (char*)As[buf] + Pb0);
    gload16(Ab + (size_t)(m0 + row1) * K2 + (size_t)k0 * 2 + kb1, (char*)As[buf] + Pb1);
    gload16(Bb + (size_t)(n0 + row0) * K2 + (size_t)k0 * 2 + kb0, (char*)Bs[buf] + Pb0);
    gload16(Bb + (size_t)(n0 + row1) * K2 + (size_t)k0 * 2 + kb1, (char*)Bs[buf] + Pb1);
  };

  STAGE(0, 0);
  __syncthreads();
  int cur = 0;
  for (int k0 = 0; k0 < K; k0 += BK) {
    if (k0 + BK < K) STAGE(cur ^ 1, k0 + BK);
    bf16x8 af[4], bfr[4];
#pragma unroll
    for (int m = 0; m < 4; m++)
      af[m] = *(const bf16x8*)((const char*)As[cur] +
               (wr + m * 16 + (lane & 15)) * 64 + ((lane >> 4) << 4));
#pragma unroll
    for (int n = 0; n < 4; n++)
      bfr[n] = *(const bf16x8*)((const char*)Bs[cur] +
               (wc + n * 16 + (lane & 15)) * 64 + ((lane >> 4) << 4));
#pragma unroll
    for (int m = 0; m < 4; m++)
#pragma unroll
      for (int n = 0; n < 4; n++)
        acc[m][n] = __builtin_amdgcn_mfma_f32_16x16x32_bf16(af[m], bfr[n], acc[m][n], 0, 0, 0);
    __syncthreads();
    cur ^= 1;
  }

#pragma unroll
  for (int m = 0; m < 4; m++) {
    const int r0 = m0 + wr + m * 16 + ((lane >> 4) << 2);
#pragma unroll
    for (int n = 0; n < 4; n++) {
      const int c = n0 + wc + n * 16 + (lane & 15);
#pragma unroll
      for (int j = 0; j < 4; j++)
        C[(size_t)(r0 + j) * N + c] = acc[m][n][j];
    }
  }
}

// ---- 64x128 tile variant (for skinny-N K/V projections: 2x the blocks) ----
__global__ __launch_bounds__(256) void gemm_bt64(const u16* __restrict__ A,
                                                 const u16* __restrict__ Bw,
                                                 float* __restrict__ C,
                                                 int M, int N, int K) {
  __shared__ u16 As[2][64 * BK];   // 4KB each
  __shared__ u16 Bs[2][BN * BK];   // 8KB each
  const int t = threadIdx.x;
  const int lane = t & 63;
  const int w = t >> 6;
  const int wc = w * 32;
  const int m0 = blockIdx.y * 64;
  const int n0 = blockIdx.x * BN;

  f32x4 acc[4][2] = {};

  const char* Ab = (const char*)A;
  const char* Bb = (const char*)Bw;
  const size_t K2 = (size_t)K * 2;

  const int P0 = t * 16;
  const int row0 = P0 >> 6, kb0 = P0 & 63;
  const int P1 = 4096 + t * 16;
  const int row1 = P1 >> 6, kb1 = P1 & 63;
  const int Pb0 = (w << 10), Pb1 = 4096 + (w << 10);

  auto STAGE = [&](int buf, int k0) {
    gload16(Ab + (size_t)(m0 + row0) * K2 + (size_t)k0 * 2 + kb0, (char*)As[buf] + Pb0);
    gload16(Bb + (size_t)(n0 + row0) * K2 + (size_t)k0 * 2 + kb0, (char*)Bs[buf] + Pb0);
    gload16(Bb + (size_t)(n0 + row1) * K2 + (size_t)k0 * 2 + kb1, (char*)Bs[buf] + Pb1);
  };

  STAGE(0, 0);
  __syncthreads();
  int cur = 0;
  for (int k0 = 0; k0 < K; k0 += BK) {
    if (k0 + BK < K) STAGE(cur ^ 1, k0 + BK);
    bf16x8 af[4], bfr[2];
#pragma unroll
    for (int m = 0; m < 4; m++)
      af[m] = *(const bf16x8*)((const char*)As[cur] +
               (m * 16 + (lane & 15)) * 64 + ((lane >> 4) << 4));
#pragma unroll
    for (int n = 0; n < 2; n++)
      bfr[n] = *(const bf16x8*)((const char*)Bs[cur] +
               (wc + n * 16 + (lane & 15)) * 64 + ((lane >> 4) << 4));
#pragma unroll
    for (int m = 0; m < 4; m++)
#pragma unroll
      for (int n = 0; n < 2; n++)
        acc[m][n] = __builtin_amdgcn_mfma_f32_16x16x32_bf16(af[m], bfr[n], acc[m][n], 0, 0, 0);
    __syncthreads();
    cur ^= 1;
  }

#pragma unroll
  for (int m = 0; m < 4; m++) {
    const int r0 = m0 + m * 16 + ((lane >> 4) << 2);
#pragma unroll
    for (int n = 0; n < 2; n++) {
      const int c = n0 + wc + n * 16 + (lane & 15);
#pragma unroll
      for (int j = 0; j < 4; j++)
        C[(size_t)(r0 + j) * N + c] = acc[m][n][j];
    }
  }
}

// ---------------- fused RMSNorm + RoPE, fp32 -> bf16, (b,s,h,d)->(b,h,s,d) --
__global__ void fuse_norm_rope(const float* __restrict__ In, const float* __restrict__ cosT,
                               const float* __restrict__ sinT, const float* __restrict__ wgt,
                               u16* __restrict__ OutT, int NH, float oscale) {
  const int r = blockIdx.x * 4 + (threadIdx.x >> 6);  // row over (b,s,h)
  const int lane = threadIdx.x & 63;
  const int h = r % NH;
  const int bs = r / NH;
  const int s = bs & (S_ - 1);
  const int b = bs >> 11;  // S_ = 2048
  float x = In[(size_t)r * 64 + lane];
  float ss = x * x;
#pragma unroll
  for (int m = 1; m < 64; m <<= 1) ss += __shfl_xor(ss, m, 64);
  float xn = x * rsqrtf(ss * (1.0f / 64.0f) + 1e-6f) * wgt[lane];
  float pr = __shfl_xor(xn, 32, 64);
  float o = xn * cosT[s * 64 + lane] + (lane < 32 ? -pr : pr) * sinT[s * 64 + lane];
  OutT[(((size_t)(b * NH + h)) * S_ + s) * 64 + lane] = f2bf(o * oscale);
}

// ---------------- V: fp32 (b,s,kvh,d) -> bf16 (b,kvh,d,s) -------------------
__global__ void v_transpose(const float* __restrict__ Vf, u16* __restrict__ Vt) {
  __shared__ u16 tile[64][72];
  const int s0 = blockIdx.x * 64;
  const int bk = blockIdx.y;
  const int b = bk / KVH_, kvh = bk % KVH_;
  const int t = threadIdx.x;
#pragma unroll
  for (int it = 0; it < 16; it++) {
    int idx = it * 256 + t;
    int sl = idx >> 6, d = idx & 63;
    tile[sl][d] = f2bf(Vf[((size_t)(b * S_ + s0 + sl)) * (KVH_ * HD_) + kvh * HD_ + d]);
  }
  __syncthreads();
#pragma unroll
  for (int it = 0; it < 16; it++) {
    int idx = it * 256 + t;
    int d = idx >> 6, sl = idx & 63;
    Vt[(((size_t)(b * KVH_ + kvh)) * HD_ + d) * S_ + s0 + sl] = tile[sl][d];
  }
}

// ---------------- flash attention, causal GQA -------------------------------
// grid: (S/64, B*H); 4 waves x 16 q-rows. Q pre-scaled by log2e/8.
// 2-phase double-buffered K/V staging; row-sum via MFMA-with-ones; defer-max.
__global__ __launch_bounds__(256) void attn_fwd(const u16* __restrict__ Qt,
                                                const u16* __restrict__ Kt,
                                                const u16* __restrict__ Vt,
                                                u16* __restrict__ Out) {
  __shared__ u16 Ksm[2][64 * 64];   // [key][d], XOR-swizzled 128B rows
  __shared__ u16 Vsm[2][64 * 64];   // [d][key], XOR-swizzled 128B rows
  __shared__ u16 Psm[4][16 * 64];   // per-wave P tile, swizzled

  const int t = threadIdx.x, lane = t & 63, w = t >> 6;
  const int qt = blockIdx.x;
  const int bh = blockIdx.y;
  const int b = bh / H_, h = bh % H_, kvh = h >> 2;  // NREP=4
  const int q0 = qt * 64 + w * 16;

  bf16x8 aq[2];
  {
    const u16* qp = Qt + (((size_t)(b * H_ + h)) * S_ + q0 + (lane & 15)) * HD_ + ((lane >> 4) << 3);
    aq[0] = *(const bf16x8*)qp;
    aq[1] = *(const bf16x8*)(qp + 32);
  }

  f32x4 o_acc[4] = {};
  float m_i[4], l_i[4];
#pragma unroll
  for (int j = 0; j < 4; j++) { m_i[j] = -1e30f; l_i[j] = 0.0f; }

  const char* Kb = (const char*)(Kt + ((size_t)(b * KVH_ + kvh)) * S_ * HD_);
  const char* Vb = (const char*)(Vt + ((size_t)(b * KVH_ + kvh)) * HD_ * S_);

  // staging addresses (per lane, swizzled global source, linear LDS dest)
  const int SP0 = t * 16, SP1 = 4096 + t * 16;
  const int srow0 = SP0 >> 7, scb0 = (SP0 ^ ((srow0 & 7) << 4)) & 127;
  const int srow1 = SP1 >> 7, scb1 = (SP1 ^ ((srow1 & 7) << 4)) & 127;
  const int SB0 = (w << 10), SB1 = 4096 + (w << 10);

  auto STAGE = [&](int buf, int kt) {
    gload16(Kb + (size_t)(kt * 64 + srow0) * 128 + scb0, (char*)Ksm[buf] + SB0);
    gload16(Kb + (size_t)(kt * 64 + srow1) * 128 + scb1, (char*)Ksm[buf] + SB1);
    gload16(Vb + (size_t)srow0 * (S_ * 2) + (size_t)kt * 128 + scb0, (char*)Vsm[buf] + SB0);
    gload16(Vb + (size_t)srow1 * (S_ * 2) + (size_t)kt * 128 + scb1, (char*)Vsm[buf] + SB1);
  };

  bf16x8 ones;
#pragma unroll
  for (int j = 0; j < 8; j++) ones[j] = (short)0x3F80;

  STAGE(0, 0);
  __syncthreads();
  int cur = 0;

  for (int kt = 0; kt <= qt; kt++) {
    if (kt < qt) STAGE(cur ^ 1, kt + 1);

    // scores: S[q][kk] = sum_d Q[q][d] K[kk][d]
    f32x4 sc[4];
    __builtin_amdgcn_s_setprio(1);
#pragma unroll
    for (int nt = 0; nt < 4; nt++) {
      f32x4 s = {};
      const int kk = nt * 16 + (lane & 15);
#pragma unroll
      for (int hh = 0; hh < 2; hh++) {
        const int byt = (kk * 128 + hh * 64 + ((lane >> 4) << 4)) ^ ((kk & 7) << 4);
        bf16x8 bk = *(const bf16x8*)((const char*)Ksm[cur] + byt);
        s = __builtin_amdgcn_mfma_f32_16x16x32_bf16(aq[hh], bk, s, 0, 0, 0);
      }
      sc[nt] = s;
    }
    __builtin_amdgcn_s_setprio(0);

    // online softmax (log2 domain; Q carries the 1/8*log2e scale)
    const bool diag = (kt == qt);
    float tmax[4];
#pragma unroll
    for (int j = 0; j < 4; j++) tmax[j] = -1e30f;
#pragma unroll
    for (int nt = 0; nt < 4; nt++) {
      const int kkg = kt * 64 + nt * 16 + (lane & 15);
#pragma unroll
      for (int j = 0; j < 4; j++) {
        float v = sc[nt][j];
        const int qg = q0 + ((lane >> 4) << 2) + j;
        if (diag && kkg > qg) v = -1e30f;
        sc[nt][j] = v;
        tmax[j] = fmaxf(tmax[j], v);
      }
    }
#pragma unroll
    for (int j = 0; j < 4; j++) {
      float v = tmax[j];
      v = fmaxf(v, __shfl_xor(v, 1, 16));
      v = fmaxf(v, __shfl_xor(v, 2, 16));
      v = fmaxf(v, __shfl_xor(v, 4, 16));
      v = fmaxf(v, __shfl_xor(v, 8, 16));
      tmax[j] = v;  // tile max
    }
    // defer-max: only rescale when the tile max meaningfully exceeds m_i
    const bool small = (tmax[0] <= m_i[0] + 8.f) && (tmax[1] <= m_i[1] + 8.f) &&
                       (tmax[2] <= m_i[2] + 8.f) && (tmax[3] <= m_i[3] + 8.f);
    if (!__all(small)) {
#pragma unroll
      for (int j = 0; j < 4; j++) {
        const float mn = fmaxf(m_i[j], tmax[j]);
        const float a = exp2f(m_i[j] - mn);
        m_i[j] = mn;
        l_i[j] *= a;
#pragma unroll
        for (int dt = 0; dt < 4; dt++) o_acc[dt][j] *= a;
      }
    }
    // P = exp2(s - m) -> per-wave swizzled LDS
#pragma unroll
    for (int nt = 0; nt < 4; nt++) {
#pragma unroll
      for (int j = 0; j < 4; j++) {
        const float p = exp2f(sc[nt][j] - m_i[j]);
        const int qrow = ((lane >> 4) << 2) + j;
        const int byt = (qrow * 128 + (nt * 16 + (lane & 15)) * 2) ^ ((qrow & 7) << 4);
        *(u16*)((char*)Psm[w] + byt) = f2bf(p);
      }
    }

    asm volatile("s_waitcnt lgkmcnt(0)" ::: "memory");  // P writes -> P reads (same wave)
    __builtin_amdgcn_sched_barrier(0);

    // P fragments (A-operand)
    bf16x8 pa[2];
#pragma unroll
    for (int hh = 0; hh < 2; hh++) {
      const int q = lane & 15;
      const int pb = (q * 128 + hh * 64 + ((lane >> 4) << 4)) ^ ((q & 7) << 4);
      pa[hh] = *(const bf16x8*)((const char*)Psm[w] + pb);
    }

    __builtin_amdgcn_s_setprio(1);
    // row-sum via MFMA with ones (replaces 16 shfl+add)
    f32x4 rs = {};
    rs = __builtin_amdgcn_mfma_f32_16x16x32_bf16(pa[0], ones, rs, 0, 0, 0);
    rs = __builtin_amdgcn_mfma_f32_16x16x32_bf16(pa[1], ones, rs, 0, 0, 0);

    // PV: O[q][d] += P[q][kk] V[kk][d]
#pragma unroll
    for (int hh = 0; hh < 2; hh++) {
#pragma unroll
      for (int dt = 0; dt < 4; dt++) {
        const int d = dt * 16 + (lane & 15);
        const int vbyt = (d * 128 + hh * 64 + ((lane >> 4) << 4)) ^ ((d & 7) << 4);
        bf16x8 bv = *(const bf16x8*)((const char*)Vsm[cur] + vbyt);
        o_acc[dt] = __builtin_amdgcn_mfma_f32_16x16x32_bf16(pa[hh], bv, o_acc[dt], 0, 0, 0);
      }
    }
    __builtin_amdgcn_s_setprio(0);

#pragma unroll
    for (int j = 0; j < 4; j++) l_i[j] += rs[j];

    __syncthreads();
    cur ^= 1;
  }

  // epilogue: O /= l, write bf16 (b,s,h,d)
#pragma unroll
  for (int j = 0; j < 4; j++) {
    const int q = q0 + ((lane >> 4) << 2) + j;
    const float inv = 1.0f / l_i[j];
#pragma unroll
    for (int dt = 0; dt < 4; dt++)
      Out[(((size_t)b * S_ + q) * H_ + h) * HD_ + dt * 16 + (lane & 15)] =
          f2bf(o_acc[dt][j] * inv);
  }
}

// ---------------- host launch ----------------
extern "C" void kernel_launch(void* const* d_in, const int* in_sizes, int n_in,
                              void* d_out, int out_size, void* d_ws, size_t ws_size,
                              hipStream_t stream) {
  const float* x  = (const float*)d_in[0];
  const float* rc = (const float*)d_in[1];
  const float* rs = (const float*)d_in[2];
  const float* Wq = (const float*)d_in[3];
  const float* Wk = (const float*)d_in[4];
  const float* Wv = (const float*)d_in[5];
  const float* Wo = (const float*)d_in[6];
  const float* qw = (const float*)d_in[7];
  const float* kw = (const float*)d_in[8];
  float* out = (float*)d_out;

  char* ws = (char*)d_ws;
  const size_t MB = (size_t)1 << 20;
  u16*   xb  = (u16*)(ws + 0 * MB);    // 16 MB bf16 x      (reused as attn-out)
  u16*   wb  = (u16*)(ws + 16 * MB);   // 8 MB  bf16 weight slot (reused 4x)
  float* Kf  = (float*)(ws + 24 * MB); // 8 MB  fp32 K-proj
  float* Vf  = (float*)(ws + 32 * MB); // 8 MB  fp32 V-proj
  u16*   Qtb = (u16*)(ws + 40 * MB);   // 16 MB bf16 Q (b,h,s,d)
  u16*   Ktb = (u16*)(ws + 56 * MB);   // 4 MB  bf16 K (b,kvh,s,d)
  u16*   Vtb = (u16*)(ws + 60 * MB);   // 4 MB  bf16 V (b,kvh,d,s)  -> 64 MB total
  float* Qf  = out;                    // d_out (32 MB fp32) doubles as Q-proj scratch
  u16*   AO  = xb;                     // xb slot free after V GEMM

  const int MT = B_ * S_;              // 4096 rows
  const float QSC = 0.125f * 1.44269504089f;  // (1/sqrt(64)) * log2(e)

  cvt_bf16<<<dim3(MT * DM_ / 1024), 256, 0, stream>>>(x, xb, MT * DM_ / 4);

  // Q path
  cvt_bf16<<<dim3(DM_ * DM_ / 1024), 256, 0, stream>>>(Wq, wb, DM_ * DM_ / 4);
  gemm_bt<<<dim3(DM_ / BN, MT / BM), 256, 0, stream>>>(xb, wb, Qf, MT, DM_, DM_);
  fuse_norm_rope<<<dim3(MT * H_ / 4), 256, 0, stream>>>(Qf, rc, rs, qw, Qtb, H_, QSC);

  // K path
  cvt_bf16<<<dim3(KVH_ * HD_ * DM_ / 1024), 256, 0, stream>>>(Wk, wb, KVH_ * HD_ * DM_ / 4);
  gemm_bt64<<<dim3(KVH_ * HD_ / BN, MT / 64), 256, 0, stream>>>(xb, wb, Kf, MT, KVH_ * HD_, DM_);
  fuse_norm_rope<<<dim3(MT * KVH_ / 4), 256, 0, stream>>>(Kf, rc, rs, kw, Ktb, KVH_, 1.0f);

  // V path
  cvt_bf16<<<dim3(KVH_ * HD_ * DM_ / 1024), 256, 0, stream>>>(Wv, wb, KVH_ * HD_ * DM_ / 4);
  gemm_bt64<<<dim3(KVH_ * HD_ / BN, MT / 64), 256, 0, stream>>>(xb, wb, Vf, MT, KVH_ * HD_, DM_);
  v_transpose<<<dim3(S_ / 64, B_ * KVH_), 256, 0, stream>>>(Vf, Vtb);

  // attention
  attn_fwd<<<dim3(S_ / 64, B_ * H_), 256, 0, stream>>>(Qtb, Ktb, Vtb, AO);

  // output projection -> d_out
  cvt_bf16<<<dim3(DM_ * DM_ / 1024), 256, 0, stream>>>(Wo, wb, DM_ * DM_ / 4);
  gemm_bt<<<dim3(DM_ / BN, MT / BM), 256, 0, stream>>>(AO, wb, out, MT, DM_, DM_);
}

// Round 3
// 280.379 us; speedup vs baseline: 1.8021x; 1.3950x over previous
//
#include <hip/hip_runtime.h>
#include <stdint.h>

#define B_ 2
#define S_ 2048
#define DM_ 2048
#define H_ 32
#define KVH_ 8
#define HD_ 64

typedef unsigned short u16;
typedef unsigned int u32;
typedef __attribute__((ext_vector_type(8))) short bf16x8;
typedef __attribute__((ext_vector_type(4))) float f32x4;

static __device__ __forceinline__ u16 f2bf(float f) {
  unsigned int u = __float_as_uint(f);
  u = (u + 0x7fffu + ((u >> 16) & 1u)) >> 16;
  return (u16)u;
}

// global -> LDS direct (width 16). LDS dest = wave-uniform base + lane*16.
static __device__ __forceinline__ void gload16(const void* g, void* lds_wave_base) {
  __builtin_amdgcn_global_load_lds(
      (__attribute__((address_space(1))) unsigned int*)(uintptr_t)g,
      (__attribute__((address_space(3))) unsigned int*)(uintptr_t)lds_wave_base,
      16, 0, 0);
}

// ---------------- fp32 -> bf16 convert ----------------
__global__ void cvt_bf16(const float* __restrict__ in, u16* __restrict__ out, int n4) {
  int i = blockIdx.x * blockDim.x + threadIdx.x;
  if (i >= n4) return;
  const float4 v = ((const float4*)in)[i];
  ushort4 o;
  o.x = f2bf(v.x); o.y = f2bf(v.y); o.z = f2bf(v.z); o.w = f2bf(v.w);
  ((ushort4*)out)[i] = o;
}

// ---------------- GEMM: C(MxN) = A(MxK) * B(NxK)^T, bf16 in, fp32 out -------
#define BM 128
#define BN 128
#define BK 32

__global__ __launch_bounds__(256) void gemm_bt(const u16* __restrict__ A,
                                               const u16* __restrict__ Bw,
                                               float* __restrict__ C,
                                               int M, int N, int K) {
  __shared__ u16 As[2][BM * BK];
  __shared__ u16 Bs[2][BN * BK];
  const int t = threadIdx.x;
  const int lane = t & 63;
  const int w = t >> 6;
  const int wr = (w >> 1) * 64, wc = (w & 1) * 64;
  const int m0 = blockIdx.y * BM;
  const int n0 = blockIdx.x * BN;

  f32x4 acc[4][4] = {};

  const char* Ab = (const char*)A;
  const char* Bb = (const char*)Bw;
  const size_t K2 = (size_t)K * 2;

  const int P0 = t * 16;
  const int row0 = P0 >> 6, kb0 = P0 & 63;
  const int P1 = 4096 + t * 16;
  const int row1 = P1 >> 6, kb1 = P1 & 63;
  const int Pb0 = (w << 10), Pb1 = 4096 + (w << 10);

  auto STAGE = [&](int buf, int k0) {
    gload16(Ab + (size_t)(m0 + row0) * K2 + (size_t)k0 * 2 + kb0, (char*)As[buf] + Pb0);
    gload16(Ab + (size_t)(m0 + row1) * K2 + (size_t)k0 * 2 + kb1, (char*)As[buf] + Pb1);
    gload16(Bb + (size_t)(n0 + row0) * K2 + (size_t)k0 * 2 + kb0, (char*)Bs[buf] + Pb0);
    gload16(Bb + (size_t)(n0 + row1) * K2 + (size_t)k0 * 2 + kb1, (char*)Bs[buf] + Pb1);
  };

  STAGE(0, 0);
  __syncthreads();
  int cur = 0;
  for (int k0 = 0; k0 < K; k0 += BK) {
    if (k0 + BK < K) STAGE(cur ^ 1, k0 + BK);
    bf16x8 af[4], bfr[4];
#pragma unroll
    for (int m = 0; m < 4; m++)
      af[m] = *(const bf16x8*)((const char*)As[cur] +
               (wr + m * 16 + (lane & 15)) * 64 + ((lane >> 4) << 4));
#pragma unroll
    for (int n = 0; n < 4; n++)
      bfr[n] = *(const bf16x8*)((const char*)Bs[cur] +
               (wc + n * 16 + (lane & 15)) * 64 + ((lane >> 4) << 4));
#pragma unroll
    for (int m = 0; m < 4; m++)
#pragma unroll
      for (int n = 0; n < 4; n++)
        acc[m][n] = __builtin_amdgcn_mfma_f32_16x16x32_bf16(af[m], bfr[n], acc[m][n], 0, 0, 0);
    __syncthreads();
    cur ^= 1;
  }

#pragma unroll
  for (int m = 0; m < 4; m++) {
    const int r0 = m0 + wr + m * 16 + ((lane >> 4) << 2);
#pragma unroll
    for (int n = 0; n < 4; n++) {
      const int c = n0 + wc + n * 16 + (lane & 15);
#pragma unroll
      for (int j = 0; j < 4; j++)
        C[(size_t)(r0 + j) * N + c] = acc[m][n][j];
    }
  }
}

// ---- 64x128 tile variant (for skinny-N K/V projections) ----
__global__ __launch_bounds__(256) void gemm_bt64(const u16* __restrict__ A,
                                                 const u16* __restrict__ Bw,
                                                 float* __restrict__ C,
                                                 int M, int N, int K) {
  __shared__ u16 As[2][64 * BK];
  __shared__ u16 Bs[2][BN * BK];
  const int t = threadIdx.x;
  const int lane = t & 63;
  const int w = t >> 6;
  const int wc = w * 32;
  const int m0 = blockIdx.y * 64;
  const int n0 = blockIdx.x * BN;

  f32x4 acc[4][2] = {};

  const char* Ab = (const char*)A;
  const char* Bb = (const char*)Bw;
  const size_t K2 = (size_t)K * 2;

  const int P0 = t * 16;
  const int row0 = P0 >> 6, kb0 = P0 & 63;
  const int P1 = 4096 + t * 16;
  const int row1 = P1 >> 6, kb1 = P1 & 63;
  const int Pb0 = (w << 10), Pb1 = 4096 + (w << 10);

  auto STAGE = [&](int buf, int k0) {
    gload16(Ab + (size_t)(m0 + row0) * K2 + (size_t)k0 * 2 + kb0, (char*)As[buf] + Pb0);
    gload16(Bb + (size_t)(n0 + row0) * K2 + (size_t)k0 * 2 + kb0, (char*)Bs[buf] + Pb0);
    gload16(Bb + (size_t)(n0 + row1) * K2 + (size_t)k0 * 2 + kb1, (char*)Bs[buf] + Pb1);
  };

  STAGE(0, 0);
  __syncthreads();
  int cur = 0;
  for (int k0 = 0; k0 < K; k0 += BK) {
    if (k0 + BK < K) STAGE(cur ^ 1, k0 + BK);
    bf16x8 af[4], bfr[2];
#pragma unroll
    for (int m = 0; m < 4; m++)
      af[m] = *(const bf16x8*)((const char*)As[cur] +
               (m * 16 + (lane & 15)) * 64 + ((lane >> 4) << 4));
#pragma unroll
    for (int n = 0; n < 2; n++)
      bfr[n] = *(const bf16x8*)((const char*)Bs[cur] +
               (wc + n * 16 + (lane & 15)) * 64 + ((lane >> 4) << 4));
#pragma unroll
    for (int m = 0; m < 4; m++)
#pragma unroll
      for (int n = 0; n < 2; n++)
        acc[m][n] = __builtin_amdgcn_mfma_f32_16x16x32_bf16(af[m], bfr[n], acc[m][n], 0, 0, 0);
    __syncthreads();
    cur ^= 1;
  }

#pragma unroll
  for (int m = 0; m < 4; m++) {
    const int r0 = m0 + m * 16 + ((lane >> 4) << 2);
#pragma unroll
    for (int n = 0; n < 2; n++) {
      const int c = n0 + wc + n * 16 + (lane & 15);
#pragma unroll
      for (int j = 0; j < 4; j++)
        C[(size_t)(r0 + j) * N + c] = acc[m][n][j];
    }
  }
}

// ---------------- fused RMSNorm + RoPE ----------------
__global__ void fuse_norm_rope(const float* __restrict__ In, const float* __restrict__ cosT,
                               const float* __restrict__ sinT, const float* __restrict__ wgt,
                               u16* __restrict__ OutT, int NH, float oscale) {
  const int r = blockIdx.x * 4 + (threadIdx.x >> 6);
  const int lane = threadIdx.x & 63;
  const int h = r % NH;
  const int bs = r / NH;
  const int s = bs & (S_ - 1);
  const int b = bs >> 11;
  float x = In[(size_t)r * 64 + lane];
  float ss = x * x;
#pragma unroll
  for (int m = 1; m < 64; m <<= 1) ss += __shfl_xor(ss, m, 64);
  float xn = x * rsqrtf(ss * (1.0f / 64.0f) + 1e-6f) * wgt[lane];
  float pr = __shfl_xor(xn, 32, 64);
  float o = xn * cosT[s * 64 + lane] + (lane < 32 ? -pr : pr) * sinT[s * 64 + lane];
  OutT[(((size_t)(b * NH + h)) * S_ + s) * 64 + lane] = f2bf(o * oscale);
}

// ---------------- V: fp32 (b,s,kvh,d) -> bf16 (b,kvh,d,s) -------------------
__global__ void v_transpose(const float* __restrict__ Vf, u16* __restrict__ Vt) {
  __shared__ u16 tile[64][72];
  const int s0 = blockIdx.x * 64;
  const int bk = blockIdx.y;
  const int b = bk / KVH_, kvh = bk % KVH_;
  const int t = threadIdx.x;
#pragma unroll
  for (int it = 0; it < 16; it++) {
    int idx = it * 256 + t;
    int sl = idx >> 6, d = idx & 63;
    tile[sl][d] = f2bf(Vf[((size_t)(b * S_ + s0 + sl)) * (KVH_ * HD_) + kvh * HD_ + d]);
  }
  __syncthreads();
#pragma unroll
  for (int it = 0; it < 16; it++) {
    int idx = it * 256 + t;
    int d = idx >> 6, sl = idx & 63;
    Vt[(((size_t)(b * KVH_ + kvh)) * HD_ + d) * S_ + s0 + sl] = tile[sl][d];
  }
}

// ---------------- flash attention, causal GQA -------------------------------
// Swapped QK^T (in-register softmax), balanced q-tile pairing, XCD-aware
// block decode. grid: (16, 64) = 1024 blocks; 4 waves x 16 q-rows each.
__global__ __launch_bounds__(256, 4) void attn_fwd(const u16* __restrict__ Qt,
                                                   const u16* __restrict__ Kt,
                                                   const u16* __restrict__ Vt,
                                                   u16* __restrict__ Out) {
  __shared__ u16 Ksm[2][64 * 64];   // [key][d], XOR-swizzled 128B rows
  __shared__ u16 Vsm[2][64 * 64];   // [d][key], XOR-swizzled 128B rows
  __shared__ u16 Psm[4][16 * 64];   // per-wave P tile [q][kk], swizzled

  const int t = threadIdx.x, lane = t & 63, w = t >> 6;
  const int q = lane & 15, g = lane >> 4;

  // XCD-aware decode: blocks sharing one (b,kvh) K/V panel land on one XCD.
  const int fid = blockIdx.y * 16 + blockIdx.x;   // 0..1023
  const int xcd = fid & 7, slot = fid >> 3;       // slot 0..127
  const int kg = xcd * 2 + (slot >> 6);           // (b,kvh) group 0..15
  const int sub = slot & 63;
  const int ip = sub >> 2;                        // q-tile pair index 0..15
  const int b = kg >> 3, kvh = kg & 7;
  const int h = kvh * 4 + (sub & 3);

  const char* Kb = (const char*)(Kt + ((size_t)(b * KVH_ + kvh)) * S_ * HD_);
  const char* Vb = (const char*)(Vt + ((size_t)(b * KVH_ + kvh)) * HD_ * S_);

  // staging addresses (per lane, swizzled global source, linear LDS dest)
  const int SP0 = t * 16, SP1 = 4096 + t * 16;
  const int srow0 = SP0 >> 7, scb0 = (SP0 ^ ((srow0 & 7) << 4)) & 127;
  const int srow1 = SP1 >> 7, scb1 = (SP1 ^ ((srow1 & 7) << 4)) & 127;
  const int SB0 = (w << 10), SB1 = 4096 + (w << 10);

  auto STAGE = [&](int buf, int kt) {
    gload16(Kb + (size_t)(kt * 64 + srow0) * 128 + scb0, (char*)Ksm[buf] + SB0);
    gload16(Kb + (size_t)(kt * 64 + srow1) * 128 + scb1, (char*)Ksm[buf] + SB1);
    gload16(Vb + (size_t)srow0 * (S_ * 2) + (size_t)kt * 128 + scb0, (char*)Vsm[buf] + SB0);
    gload16(Vb + (size_t)srow1 * (S_ * 2) + (size_t)kt * 128 + scb1, (char*)Vsm[buf] + SB1);
  };

  const int swz = (q & 7) << 4;
  // kt-invariant LDS byte offsets
  int koff[4][2], voff[4][2], pwoff[4][2], proff[2];
#pragma unroll
  for (int nt = 0; nt < 4; nt++)
#pragma unroll
    for (int hh = 0; hh < 2; hh++) {
      koff[nt][hh] = ((nt * 16 + q) * 128 + hh * 64 + g * 16) ^ swz;
      voff[nt][hh] = ((nt * 16 + q) * 128 + hh * 64 + g * 16) ^ swz;  // nt==dt
      pwoff[nt][hh] = (q * 128 + nt * 32 + g * 8 + hh * 4) ^ swz;
    }
#pragma unroll
  for (int c = 0; c < 2; c++) proff[c] = (q * 128 + c * 64 + g * 16) ^ swz;

  auto process = [&](int qt) {
    const int q0w = qt * 64 + w * 16;
    bf16x8 aq[2];
    {
      const u16* qp = Qt + (((size_t)(b * H_ + h)) * S_ + q0w + q) * HD_ + g * 8;
      aq[0] = *(const bf16x8*)qp;
      aq[1] = *(const bf16x8*)(qp + 32);
    }
    f32x4 o_acc[4] = {};
    float m_i = -1e30f, l_i = 0.0f;

    STAGE(0, 0);
    __syncthreads();
    int cur = 0;

    for (int kt = 0; kt <= qt; kt++) {
      if (kt < qt) STAGE(cur ^ 1, kt + 1);

      // scores: sc[nt][r] = S[kk = nt*16 + g*4 + r][q] (swapped: A=K, B=Q)
      f32x4 sc[4];
      __builtin_amdgcn_s_setprio(1);
#pragma unroll
      for (int nt = 0; nt < 4; nt++) {
        f32x4 s = {};
#pragma unroll
        for (int hh = 0; hh < 2; hh++) {
          bf16x8 bk = *(const bf16x8*)((const char*)Ksm[cur] + koff[nt][hh]);
          s = __builtin_amdgcn_mfma_f32_16x16x32_bf16(bk, aq[hh], s, 0, 0, 0);
        }
        sc[nt] = s;
      }
      __builtin_amdgcn_s_setprio(0);

      if (kt == qt) {  // diagonal-tile causal mask (kt*64 cancels)
#pragma unroll
        for (int nt = 0; nt < 4; nt++)
#pragma unroll
          for (int r = 0; r < 4; r++)
            if (nt * 16 + g * 4 + r > w * 16 + q) sc[nt][r] = -1e30f;
      }

      // in-register max over this lane's 16 kk + 2 shfl across groups
      float mx = sc[0][0];
#pragma unroll
      for (int nt = 0; nt < 4; nt++)
#pragma unroll
        for (int r = 0; r < 4; r++) mx = fmaxf(mx, sc[nt][r]);
      mx = fmaxf(mx, __shfl_xor(mx, 16, 64));
      mx = fmaxf(mx, __shfl_xor(mx, 32, 64));

      // defer-max (THR=8 in log2 domain)
      if (!__all(mx <= m_i + 8.0f)) {
        const float mn = fmaxf(m_i, mx);
        const float a = exp2f(m_i - mn);
        m_i = mn;
        l_i *= a;
        float aT[4];
#pragma unroll
        for (int r = 0; r < 4; r++)
          aT[r] = __shfl(a, (lane & 48) + ((lane & 48) >> 2) + r, 64);
#pragma unroll
        for (int dt = 0; dt < 4; dt++)
#pragma unroll
          for (int r = 0; r < 4; r++) o_acc[dt][r] *= aT[r];
      }

      // P = exp2(sc - m), row-sum, pack pairs -> per-wave LDS
      float rs = 0.0f;
#pragma unroll
      for (int nt = 0; nt < 4; nt++)
#pragma unroll
        for (int r = 0; r < 4; r++) {
          const float pv = exp2f(sc[nt][r] - m_i);
          sc[nt][r] = pv;
          rs += pv;
        }
      rs += __shfl_xor(rs, 16, 64);
      rs += __shfl_xor(rs, 32, 64);
      l_i += rs;

#pragma unroll
      for (int nt = 0; nt < 4; nt++)
#pragma unroll
        for (int hh = 0; hh < 2; hh++) {
          u32 wv;
          asm("v_cvt_pk_bf16_f32 %0, %1, %2"
              : "=v"(wv) : "v"(sc[nt][2 * hh]), "v"(sc[nt][2 * hh + 1]));
          *(u32*)((char*)Psm[w] + pwoff[nt][hh]) = wv;
        }

      asm volatile("s_waitcnt lgkmcnt(0)" ::: "memory");
      __builtin_amdgcn_sched_barrier(0);

      bf16x8 pa[2];
#pragma unroll
      for (int c = 0; c < 2; c++)
        pa[c] = *(const bf16x8*)((const char*)Psm[w] + proff[c]);

      __builtin_amdgcn_s_setprio(1);
#pragma unroll
      for (int c = 0; c < 2; c++)
#pragma unroll
        for (int dt = 0; dt < 4; dt++) {
          bf16x8 bv = *(const bf16x8*)((const char*)Vsm[cur] + voff[dt][c]);
          o_acc[dt] = __builtin_amdgcn_mfma_f32_16x16x32_bf16(pa[c], bv, o_acc[dt], 0, 0, 0);
        }
      __builtin_amdgcn_s_setprio(0);

      __syncthreads();
      cur ^= 1;
    }

    // epilogue: transpose l into O domain, divide, write bf16 (b,s,h,d)
    float lT[4];
#pragma unroll
    for (int r = 0; r < 4; r++)
      lT[r] = __shfl(l_i, (lane & 48) + ((lane & 48) >> 2) + r, 64);
#pragma unroll
    for (int r = 0; r < 4; r++) {
      const int qg = q0w + g * 4 + r;
      const float inv = 1.0f / lT[r];
#pragma unroll
      for (int dt = 0; dt < 4; dt++)
        Out[(((size_t)b * S_ + qg) * H_ + h) * HD_ + dt * 16 + q] =
            f2bf(o_acc[dt][r] * inv);
    }
  };

  process(ip);
  process(31 - ip);
}

// ---------------- host launch ----------------
extern "C" void kernel_launch(void* const* d_in, const int* in_sizes, int n_in,
                              void* d_out, int out_size, void* d_ws, size_t ws_size,
                              hipStream_t stream) {
  const float* x  = (const float*)d_in[0];
  const float* rc = (const float*)d_in[1];
  const float* rs = (const float*)d_in[2];
  const float* Wq = (const float*)d_in[3];
  const float* Wk = (const float*)d_in[4];
  const float* Wv = (const float*)d_in[5];
  const float* Wo = (const float*)d_in[6];
  const float* qw = (const float*)d_in[7];
  const float* kw = (const float*)d_in[8];
  float* out = (float*)d_out;

  char* ws = (char*)d_ws;
  const size_t MB = (size_t)1 << 20;
  u16*   xb  = (u16*)(ws + 0 * MB);
  u16*   wb  = (u16*)(ws + 16 * MB);
  float* Kf  = (float*)(ws + 24 * MB);
  float* Vf  = (float*)(ws + 32 * MB);
  u16*   Qtb = (u16*)(ws + 40 * MB);
  u16*   Ktb = (u16*)(ws + 56 * MB);
  u16*   Vtb = (u16*)(ws + 60 * MB);
  float* Qf  = out;
  u16*   AO  = xb;

  const int MT = B_ * S_;
  const float QSC = 0.125f * 1.44269504089f;

  cvt_bf16<<<dim3(MT * DM_ / 1024), 256, 0, stream>>>(x, xb, MT * DM_ / 4);

  // Q path
  cvt_bf16<<<dim3(DM_ * DM_ / 1024), 256, 0, stream>>>(Wq, wb, DM_ * DM_ / 4);
  gemm_bt<<<dim3(DM_ / BN, MT / BM), 256, 0, stream>>>(xb, wb, Qf, MT, DM_, DM_);
  fuse_norm_rope<<<dim3(MT * H_ / 4), 256, 0, stream>>>(Qf, rc, rs, qw, Qtb, H_, QSC);

  // K path
  cvt_bf16<<<dim3(KVH_ * HD_ * DM_ / 1024), 256, 0, stream>>>(Wk, wb, KVH_ * HD_ * DM_ / 4);
  gemm_bt64<<<dim3(KVH_ * HD_ / BN, MT / 64), 256, 0, stream>>>(xb, wb, Kf, MT, KVH_ * HD_, DM_);
  fuse_norm_rope<<<dim3(MT * KVH_ / 4), 256, 0, stream>>>(Kf, rc, rs, kw, Ktb, KVH_, 1.0f);

  // V path
  cvt_bf16<<<dim3(KVH_ * HD_ * DM_ / 1024), 256, 0, stream>>>(Wv, wb, KVH_ * HD_ * DM_ / 4);
  gemm_bt64<<<dim3(KVH_ * HD_ / BN, MT / 64), 256, 0, stream>>>(xb, wb, Vf, MT, KVH_ * HD_, DM_);
  v_transpose<<<dim3(S_ / 64, B_ * KVH_), 256, 0, stream>>>(Vf, Vtb);

  // attention (1024 balanced blocks, q-tile pairing)
  attn_fwd<<<dim3(16, 64), 256, 0, stream>>>(Qtb, Ktb, Vtb, AO);

  // output projection -> d_out
  cvt_bf16<<<dim3(DM_ * DM_ / 1024), 256, 0, stream>>>(Wo, wb, DM_ * DM_ / 4);
  gemm_bt<<<dim3(DM_ / BN, MT / BM), 256, 0, stream>>>(AO, wb, out, MT, DM_, DM_);
}

// Round 4
// 240.123 us; speedup vs baseline: 2.1042x; 1.1676x over previous
//
#include <hip/hip_runtime.h>
#include <stdint.h>

#define B_ 2
#define S_ 2048
#define DM_ 2048
#define H_ 32
#define KVH_ 8
#define HD_ 64
#define NQK_ 3072   // 2048 q + 512 k + 512 v

typedef unsigned short u16;
typedef unsigned int u32;
typedef __attribute__((ext_vector_type(8))) short bf16x8;
typedef __attribute__((ext_vector_type(4))) float f32x4;

static __device__ __forceinline__ u16 f2bf(float f) {
  unsigned int u = __float_as_uint(f);
  u = (u + 0x7fffu + ((u >> 16) & 1u)) >> 16;
  return (u16)u;
}
static __device__ __forceinline__ float bf2f(u16 v) {
  unsigned int u = ((unsigned int)v) << 16;
  return __uint_as_float(u);
}

// global -> LDS direct (width 16). LDS dest = wave-uniform base + lane*16.
static __device__ __forceinline__ void gload16(const void* g, void* lds_wave_base) {
  __builtin_amdgcn_global_load_lds(
      (__attribute__((address_space(1))) unsigned int*)(uintptr_t)g,
      (__attribute__((address_space(3))) unsigned int*)(uintptr_t)lds_wave_base,
      16, 0, 0);
}

// ---------------- fp32 -> bf16 convert ----------------
__global__ void cvt_bf16(const float* __restrict__ in, u16* __restrict__ out, int n4) {
  int i = blockIdx.x * blockDim.x + threadIdx.x;
  if (i >= n4) return;
  const float4 v = ((const float4*)in)[i];
  ushort4 o;
  o.x = f2bf(v.x); o.y = f2bf(v.y); o.z = f2bf(v.z); o.w = f2bf(v.w);
  ((ushort4*)out)[i] = o;
}

// ---------------- GEMM: C(MxN) = A(MxK) * B(NxK)^T, bf16 in ----------------
// 128x128 tile, 2-phase double-buffered staging. fp32-out and bf16-out twins.
#define BM 128
#define BN 128
#define BK 32

#define GEMM_BODY(CSTORE)                                                       \
  __shared__ u16 As[2][BM * BK];                                                \
  __shared__ u16 Bs[2][BN * BK];                                                \
  const int t = threadIdx.x;                                                    \
  const int lane = t & 63;                                                      \
  const int w = t >> 6;                                                         \
  const int wr = (w >> 1) * 64, wc = (w & 1) * 64;                              \
  const int m0 = blockIdx.y * BM;                                               \
  const int n0 = blockIdx.x * BN;                                               \
  f32x4 acc[4][4] = {};                                                         \
  const char* Ab = (const char*)A;                                              \
  const char* Bb = (const char*)Bw;                                             \
  const size_t K2 = (size_t)K * 2;                                              \
  const int P0 = t * 16;                                                        \
  const int row0 = P0 >> 6, kb0 = P0 & 63;                                      \
  const int P1 = 4096 + t * 16;                                                 \
  const int row1 = P1 >> 6, kb1 = P1 & 63;                                      \
  const int Pb0 = (w << 10), Pb1 = 4096 + (w << 10);                            \
  auto STAGE = [&](int buf, int k0) {                                           \
    gload16(Ab + (size_t)(m0 + row0) * K2 + (size_t)k0 * 2 + kb0, (char*)As[buf] + Pb0); \
    gload16(Ab + (size_t)(m0 + row1) * K2 + (size_t)k0 * 2 + kb1, (char*)As[buf] + Pb1); \
    gload16(Bb + (size_t)(n0 + row0) * K2 + (size_t)k0 * 2 + kb0, (char*)Bs[buf] + Pb0); \
    gload16(Bb + (size_t)(n0 + row1) * K2 + (size_t)k0 * 2 + kb1, (char*)Bs[buf] + Pb1); \
  };                                                                            \
  STAGE(0, 0);                                                                  \
  __syncthreads();                                                              \
  int cur = 0;                                                                  \
  for (int k0 = 0; k0 < K; k0 += BK) {                                          \
    if (k0 + BK < K) STAGE(cur ^ 1, k0 + BK);                                   \
    bf16x8 af[4], bfr[4];                                                       \
    _Pragma("unroll")                                                           \
    for (int m = 0; m < 4; m++)                                                 \
      af[m] = *(const bf16x8*)((const char*)As[cur] +                           \
               (wr + m * 16 + (lane & 15)) * 64 + ((lane >> 4) << 4));          \
    _Pragma("unroll")                                                           \
    for (int n = 0; n < 4; n++)                                                 \
      bfr[n] = *(const bf16x8*)((const char*)Bs[cur] +                          \
               (wc + n * 16 + (lane & 15)) * 64 + ((lane >> 4) << 4));          \
    _Pragma("unroll")                                                           \
    for (int m = 0; m < 4; m++)                                                 \
      _Pragma("unroll")                                                         \
      for (int n = 0; n < 4; n++)                                               \
        acc[m][n] = __builtin_amdgcn_mfma_f32_16x16x32_bf16(af[m], bfr[n], acc[m][n], 0, 0, 0); \
    __syncthreads();                                                            \
    cur ^= 1;                                                                   \
  }                                                                             \
  _Pragma("unroll")                                                             \
  for (int m = 0; m < 4; m++) {                                                 \
    const int r0 = m0 + wr + m * 16 + ((lane >> 4) << 2);                       \
    _Pragma("unroll")                                                           \
    for (int n = 0; n < 4; n++) {                                               \
      const int c = n0 + wc + n * 16 + (lane & 15);                             \
      _Pragma("unroll")                                                         \
      for (int j = 0; j < 4; j++) CSTORE;                                       \
    }                                                                           \
  }

__global__ __launch_bounds__(256) void gemm_bt(const u16* __restrict__ A,
                                               const u16* __restrict__ Bw,
                                               float* __restrict__ C,
                                               int M, int N, int K) {
  GEMM_BODY(C[(size_t)(r0 + j) * N + c] = acc[m][n][j])
}

__global__ __launch_bounds__(256) void gemm_btb(const u16* __restrict__ A,
                                                const u16* __restrict__ Bw,
                                                u16* __restrict__ C,
                                                int M, int N, int K) {
  GEMM_BODY(C[(size_t)(r0 + j) * N + c] = f2bf(acc[m][n][j]))
}

// ------- fused RMSNorm + RoPE, in-place on bf16 QKV buffer (b,s,[q|k]) ------
// one wave per (row, head); head index hh2 in [0,40): 0-31 = Q heads, 32-39 = K.
__global__ void norm_rope_inplace(u16* __restrict__ QKV, const float* __restrict__ cosT,
                                  const float* __restrict__ sinT,
                                  const float* __restrict__ qw,
                                  const float* __restrict__ kw, float qscale) {
  const int r = blockIdx.x * 4 + (threadIdx.x >> 6);
  const int lane = threadIdx.x & 63;
  const int hh2 = r % 40;
  const int bs = r / 40;
  const int s = bs & (S_ - 1);
  const bool isq = hh2 < 32;
  u16* p = QKV + (size_t)bs * NQK_ + hh2 * 64 + lane;
  float x = bf2f(*p);
  float ss = x * x;
#pragma unroll
  for (int m = 1; m < 64; m <<= 1) ss += __shfl_xor(ss, m, 64);
  const float wgt = isq ? qw[lane] : kw[lane];
  float xn = x * rsqrtf(ss * (1.0f / 64.0f) + 1e-6f) * wgt;
  float pr = __shfl_xor(xn, 32, 64);
  float o = xn * cosT[s * 64 + lane] + (lane < 32 ? -pr : pr) * sinT[s * 64 + lane];
  *p = f2bf(o * (isq ? qscale : 1.0f));
}

// -------- V: bf16 QKV v-part (b,s,kvh,d) -> bf16 (b,kvh,d,s) ---------------
__global__ void v_transpose(const u16* __restrict__ QKV, u16* __restrict__ Vt) {
  __shared__ u16 tile[64][72];
  const int s0 = blockIdx.x * 64;
  const int bk = blockIdx.y;
  const int b = bk / KVH_, kvh = bk % KVH_;
  const int t = threadIdx.x;
#pragma unroll
  for (int it = 0; it < 16; it++) {
    int idx = it * 256 + t;
    int sl = idx >> 6, d = idx & 63;
    tile[sl][d] = QKV[(size_t)(b * S_ + s0 + sl) * NQK_ + 2560 + kvh * 64 + d];
  }
  __syncthreads();
#pragma unroll
  for (int it = 0; it < 16; it++) {
    int idx = it * 256 + t;
    int d = idx >> 6, sl = idx & 63;
    Vt[(((size_t)(b * KVH_ + kvh)) * HD_ + d) * S_ + s0 + sl] = tile[sl][d];
  }
}

// ---------------- flash attention, causal GQA -------------------------------
// Swapped QK^T, in-register softmax, l via MFMA-ones (O-domain), balanced
// q-tile pairing, XCD-aware decode. Q/K read straight from QKV buffer.
__global__ __launch_bounds__(256, 4) void attn_fwd(const u16* __restrict__ QKV,
                                                   const u16* __restrict__ Vt,
                                                   u16* __restrict__ Out) {
  __shared__ u16 Ksm[2][64 * 64];   // [key][d], XOR-swizzled 128B rows
  __shared__ u16 Vsm[2][64 * 64];   // [d][key], XOR-swizzled 128B rows
  __shared__ u16 Psm[4][16 * 64];   // per-wave P tile [q][kk], swizzled

  const int t = threadIdx.x, lane = t & 63, w = t >> 6;
  const int q = lane & 15, g = lane >> 4;

  // XCD-aware decode: blocks sharing one (b,kvh) K/V panel land on one XCD.
  const int fid = blockIdx.y * 16 + blockIdx.x;   // 0..1023
  const int xcd = fid & 7, slot = fid >> 3;       // slot 0..127
  const int kg = xcd * 2 + (slot >> 6);           // (b,kvh) group 0..15
  const int sub = slot & 63;
  const int ip = sub >> 2;                        // q-tile pair index 0..15
  const int b = kg >> 3, kvh = kg & 7;
  const int h = kvh * 4 + (sub & 3);

  // K rows live inside QKV: row (b,s), cols [2048 + kvh*64, +64) -> 128B chunk
  const char* Kb = (const char*)(QKV + (size_t)b * S_ * NQK_ + 2048 + kvh * 64);
  const char* Vb = (const char*)(Vt + ((size_t)(b * KVH_ + kvh)) * HD_ * S_);

  // staging addresses (per lane, swizzled global source, linear LDS dest)
  const int SP0 = t * 16, SP1 = 4096 + t * 16;
  const int srow0 = SP0 >> 7, scb0 = (SP0 ^ ((srow0 & 7) << 4)) & 127;
  const int srow1 = SP1 >> 7, scb1 = (SP1 ^ ((srow1 & 7) << 4)) & 127;
  const int SB0 = (w << 10), SB1 = 4096 + (w << 10);
  const size_t KROW = (size_t)NQK_ * 2;  // 6144B row stride inside QKV

  auto STAGE = [&](int buf, int kt) {
    gload16(Kb + (size_t)(kt * 64 + srow0) * KROW + scb0, (char*)Ksm[buf] + SB0);
    gload16(Kb + (size_t)(kt * 64 + srow1) * KROW + scb1, (char*)Ksm[buf] + SB1);
    gload16(Vb + (size_t)srow0 * (S_ * 2) + (size_t)kt * 128 + scb0, (char*)Vsm[buf] + SB0);
    gload16(Vb + (size_t)srow1 * (S_ * 2) + (size_t)kt * 128 + scb1, (char*)Vsm[buf] + SB1);
  };

  const int swz = (q & 7) << 4;
  int koff[4][2], voff[4][2], pwoff[4][2], proff[2];
#pragma unroll
  for (int nt = 0; nt < 4; nt++)
#pragma unroll
    for (int hh = 0; hh < 2; hh++) {
      koff[nt][hh] = ((nt * 16 + q) * 128 + hh * 64 + g * 16) ^ swz;
      voff[nt][hh] = ((nt * 16 + q) * 128 + hh * 64 + g * 16) ^ swz;
      pwoff[nt][hh] = (q * 128 + nt * 32 + g * 8 + hh * 4) ^ swz;
    }
#pragma unroll
  for (int c = 0; c < 2; c++) proff[c] = (q * 128 + c * 64 + g * 16) ^ swz;

  bf16x8 ones;
#pragma unroll
  for (int j = 0; j < 8; j++) ones[j] = (short)0x3F80;

  auto process = [&](int qt) {
    const int q0w = qt * 64 + w * 16;
    bf16x8 aq[2];
    {
      const u16* qp = QKV + (size_t)(b * S_ + q0w + q) * NQK_ + h * 64 + g * 8;
      aq[0] = *(const bf16x8*)qp;
      aq[1] = *(const bf16x8*)(qp + 32);
    }
    f32x4 o_acc[4] = {};
    f32x4 l_acc = {};
    float m_i = -1e30f;

    STAGE(0, 0);
    __syncthreads();
    int cur = 0;

    for (int kt = 0; kt <= qt; kt++) {
      if (kt < qt) STAGE(cur ^ 1, kt + 1);

      // scores: sc[nt][r] = S[kk = nt*16 + g*4 + r][q] (swapped: A=K, B=Q)
      f32x4 sc[4];
      __builtin_amdgcn_s_setprio(1);
#pragma unroll
      for (int nt = 0; nt < 4; nt++) {
        f32x4 s = {};
#pragma unroll
        for (int hh = 0; hh < 2; hh++) {
          bf16x8 bk = *(const bf16x8*)((const char*)Ksm[cur] + koff[nt][hh]);
          s = __builtin_amdgcn_mfma_f32_16x16x32_bf16(bk, aq[hh], s, 0, 0, 0);
        }
        sc[nt] = s;
      }
      __builtin_amdgcn_s_setprio(0);

      if (kt == qt) {  // diagonal-tile causal mask
#pragma unroll
        for (int nt = 0; nt < 4; nt++)
#pragma unroll
          for (int r = 0; r < 4; r++)
            if (nt * 16 + g * 4 + r > w * 16 + q) sc[nt][r] = -1e30f;
      }

      // lane-local max (max3-friendly tree) + 2 shfl across 16-lane groups
      float mx;
      {
        float m0 = fmaxf(fmaxf(sc[0][0], sc[0][1]), fmaxf(sc[0][2], sc[0][3]));
        float m1 = fmaxf(fmaxf(sc[1][0], sc[1][1]), fmaxf(sc[1][2], sc[1][3]));
        float m2 = fmaxf(fmaxf(sc[2][0], sc[2][1]), fmaxf(sc[2][2], sc[2][3]));
        float m3 = fmaxf(fmaxf(sc[3][0], sc[3][1]), fmaxf(sc[3][2], sc[3][3]));
        mx = fmaxf(fmaxf(m0, m1), fmaxf(m2, m3));
      }
      mx = fmaxf(mx, __shfl_xor(mx, 16, 64));
      mx = fmaxf(mx, __shfl_xor(mx, 32, 64));

      // defer-max (THR=8 in log2 domain)
      if (!__all(mx <= m_i + 8.0f)) {
        const float mn = fmaxf(m_i, mx);
        const float a = exp2f(m_i - mn);
        m_i = mn;
        float aT[4];
#pragma unroll
        for (int r = 0; r < 4; r++)
          aT[r] = __shfl(a, (lane & 48) + ((lane & 48) >> 2) + r, 64);
#pragma unroll
        for (int r = 0; r < 4; r++) {
          l_acc[r] *= aT[r];
#pragma unroll
          for (int dt = 0; dt < 4; dt++) o_acc[dt][r] *= aT[r];
        }
      }

      // P = exp2(sc - m), pack pairs -> per-wave LDS
#pragma unroll
      for (int nt = 0; nt < 4; nt++)
#pragma unroll
        for (int r = 0; r < 4; r++) sc[nt][r] = exp2f(sc[nt][r] - m_i);
#pragma unroll
      for (int nt = 0; nt < 4; nt++)
#pragma unroll
        for (int hh = 0; hh < 2; hh++) {
          u32 wv;
          asm("v_cvt_pk_bf16_f32 %0, %1, %2"
              : "=v"(wv) : "v"(sc[nt][2 * hh]), "v"(sc[nt][2 * hh + 1]));
          *(u32*)((char*)Psm[w] + pwoff[nt][hh]) = wv;
        }

      asm volatile("s_waitcnt lgkmcnt(0)" ::: "memory");
      __builtin_amdgcn_sched_barrier(0);

      bf16x8 pa[2];
#pragma unroll
      for (int c = 0; c < 2; c++)
        pa[c] = *(const bf16x8*)((const char*)Psm[w] + proff[c]);

      __builtin_amdgcn_s_setprio(1);
      // l row-sums via MFMA-with-ones: lands directly in O-domain (g*4+r)
      l_acc = __builtin_amdgcn_mfma_f32_16x16x32_bf16(pa[0], ones, l_acc, 0, 0, 0);
      l_acc = __builtin_amdgcn_mfma_f32_16x16x32_bf16(pa[1], ones, l_acc, 0, 0, 0);
      // PV: O[q][d] += P[q][kk] V[kk][d]
#pragma unroll
      for (int c = 0; c < 2; c++)
#pragma unroll
        for (int dt = 0; dt < 4; dt++) {
          bf16x8 bv = *(const bf16x8*)((const char*)Vsm[cur] + voff[dt][c]);
          o_acc[dt] = __builtin_amdgcn_mfma_f32_16x16x32_bf16(pa[c], bv, o_acc[dt], 0, 0, 0);
        }
      __builtin_amdgcn_s_setprio(0);

      __syncthreads();
      cur ^= 1;
    }

    // epilogue: O /= l (already O-domain), write bf16 (b,s,h,d)
#pragma unroll
    for (int r = 0; r < 4; r++) {
      const int qg = q0w + g * 4 + r;
      const float inv = 1.0f / l_acc[r];
#pragma unroll
      for (int dt = 0; dt < 4; dt++)
        Out[(((size_t)b * S_ + qg) * H_ + h) * HD_ + dt * 16 + q] =
            f2bf(o_acc[dt][r] * inv);
    }
  };

  process(ip);
  process(31 - ip);
}

// ---------------- host launch ----------------
extern "C" void kernel_launch(void* const* d_in, const int* in_sizes, int n_in,
                              void* d_out, int out_size, void* d_ws, size_t ws_size,
                              hipStream_t stream) {
  const float* x  = (const float*)d_in[0];
  const float* rc = (const float*)d_in[1];
  const float* rs = (const float*)d_in[2];
  const float* Wq = (const float*)d_in[3];
  const float* Wk = (const float*)d_in[4];
  const float* Wv = (const float*)d_in[5];
  const float* Wo = (const float*)d_in[6];
  const float* qw = (const float*)d_in[7];
  const float* kw = (const float*)d_in[8];
  float* out = (float*)d_out;

  char* ws = (char*)d_ws;
  const size_t MB = (size_t)1 << 20;
  u16* xb   = (u16*)(ws + 0 * MB);    // 16 MB bf16 x (reused as attn-out)
  u16* wbq  = (u16*)(ws + 16 * MB);   // 12 MB bf16 [Wq;Wk;Wv] (then Wo reuse)
  u16* QKVb = (u16*)(ws + 28 * MB);   // 24 MB bf16 QKV proj (b,s,3072)
  u16* Vtb  = (u16*)(ws + 52 * MB);   // 4 MB  bf16 V (b,kvh,d,s)  -> 56 MB
  u16* AO   = xb;

  const int MT = B_ * S_;
  const float QSC = 0.125f * 1.44269504089f;  // (1/sqrt(64)) * log2(e)

  cvt_bf16<<<dim3(MT * DM_ / 1024), 256, 0, stream>>>(x, xb, MT * DM_ / 4);
  // concatenated QKV weights -> bf16
  cvt_bf16<<<dim3(DM_ * DM_ / 1024), 256, 0, stream>>>(Wq, wbq, DM_ * DM_ / 4);
  cvt_bf16<<<dim3(512 * DM_ / 1024), 256, 0, stream>>>(Wk, wbq + (size_t)DM_ * DM_, 512 * DM_ / 4);
  cvt_bf16<<<dim3(512 * DM_ / 1024), 256, 0, stream>>>(Wv, wbq + (size_t)DM_ * DM_ + (size_t)512 * DM_, 512 * DM_ / 4);

  // one fused QKV projection, bf16 out
  gemm_btb<<<dim3(NQK_ / BN, MT / BM), 256, 0, stream>>>(xb, wbq, QKVb, MT, NQK_, DM_);

  // RMSNorm + RoPE in place (Q scaled by log2e/8)
  norm_rope_inplace<<<dim3(MT * 40 / 4), 256, 0, stream>>>(QKVb, rc, rs, qw, kw, QSC);

  // V -> (b,kvh,d,s)
  v_transpose<<<dim3(S_ / 64, B_ * KVH_), 256, 0, stream>>>(QKVb, Vtb);

  // attention (1024 balanced blocks, q-tile pairing)
  attn_fwd<<<dim3(16, 64), 256, 0, stream>>>(QKVb, Vtb, AO);

  // output projection -> d_out (fp32)
  cvt_bf16<<<dim3(DM_ * DM_ / 1024), 256, 0, stream>>>(Wo, wbq, DM_ * DM_ / 4);
  gemm_bt<<<dim3(DM_ / BN, MT / BM), 256, 0, stream>>>(AO, wbq, out, MT, DM_, DM_);
}